// Round 7
// baseline (173.845 us; speedup 1.0000x reference)
//
#include <hip/hip_runtime.h>

#define THREADS 128   // 2 waves/block; 8 blocks/CU = 16 waves/CU = 4 waves/SIMD
#define IPB 4         // images per block; grid = 8192/4 = 2048 = 256 CU x 8
// Geometry rationale (R7): at 32 waves/CU the unified-RF cap is 64 regs/lane
// and the compiler's VGPR/AGPR partition leaves ~32 arch VGPRs -> conv1 (~50
// live) spills in EVERY variant (R2: 8.5MB, R4: 66MB, R6: 5.3MB). 16 waves/CU
// gives 128 regs/lane: genuinely spill-free. VALU-issue-bound conv1 doesn't
// need 8 waves/SIMD (2-cyc pipe covered by 2); grid stays one resident round.

typedef _Float16 f16;
typedef _Float16 f16x2 __attribute__((ext_vector_type(2)));
typedef _Float16 f16x8 __attribute__((ext_vector_type(8)));
typedef float f32x2 __attribute__((ext_vector_type(2)));
typedef float f32x4 __attribute__((ext_vector_type(4)));
typedef float f32x16 __attribute__((ext_vector_type(16)));
typedef unsigned int uint;

__device__ __forceinline__ f16x2 pkrtz(float a, float b) {
    return __builtin_bit_cast(f16x2, __builtin_amdgcn_cvt_pkrtz(a, b));
}
template<int CTRL>
__device__ __forceinline__ float dppmax(float v) {   // fmax with DPP-shuffled lane
    const int i = __builtin_bit_cast(int, v);
    const int s = __builtin_amdgcn_update_dpp(i, i, CTRL, 0xF, 0xF, true);
    return fmaxf(v, __builtin_bit_cast(float, s));
}
// load one 6-px row slice starting at rp (8B aligned), make 5 shifted pairs
__device__ __forceinline__ void loadrow(const float* rp, f16x2* p) {
    const f32x2 a01 = *(const f32x2*)(rp);
    const f32x2 a23 = *(const f32x2*)(rp + 2);
    const f32x2 a45 = *(const f32x2*)(rp + 4);
    p[0] = pkrtz(a01[0], a01[1]);
    p[1] = pkrtz(a01[1], a23[0]);
    p[2] = pkrtz(a23[0], a23[1]);
    p[3] = pkrtz(a23[1], a45[0]);
    p[4] = pkrtz(a45[0], a45[1]);
}

// p1 layout: [img][iy 12][ix 12][ic 16] f16. Row stride 400B; final row unpadded
// so img stride = 11*400+384 = 4784B. ic 10..15 zeros (K-pad).
#define P1_ROW 400
#define P1_IMG 4784
// LDS: single 19136 B block; 8 blocks/CU = 153 KB <= 160 KB. p2h/h1 ALIAS p1c
// (p1c dead after conv2 MFMA loops; barrier separates last read from write).
#define SMEM_BYTES 19136

// d_ws layout: [0)      w1pk   250 x uint (dup f16 pairs)
//              [1024)   w2af   1000 x f16x8  (conv2 A-frags [s][oc*2+hK])
//              [17408)  wl1pk  2560 x f16x8  (fc1 A-frags [tile][s][lane])
__global__ void pack_weights(const float* __restrict__ w1,
                             const float* __restrict__ w2,
                             const float* __restrict__ wl1,
                             unsigned char* __restrict__ ws) {
    uint* w1pk  = (uint*)ws;
    f16x8* w2af = (f16x8*)(ws + 1024);
    f16x8* wl1pk = (f16x8*)(ws + 17408);
    const int gid = blockIdx.x * blockDim.x + threadIdx.x;
    const int gsz = gridDim.x * blockDim.x;
    for (int i = gid; i < 250; i += gsz) {
        const unsigned short u =
            __builtin_bit_cast(unsigned short, (f16)w1[i]);
        w1pk[i] = (uint)u | ((uint)u << 16);
    }
    for (int e = gid; e < 1000; e += gsz) {          // conv2 A-frags
        const int s = e / 40, r = e - s * 40;
        const int oc = r >> 1, h = r & 1;
        f16x8 a;
        #pragma unroll
        for (int j = 0; j < 8; ++j) {
            const int ic = h * 8 + j;
            a[j] = (f16)(ic < 10 ? w2[(oc * 10 + ic) * 25 + s] : 0.f);
        }
        w2af[e] = a;
    }
    for (int e = gid; e < 2560; e += gsz) {          // fc1 A-frags
        const int tile = e / 640, rem = e % 640;
        const int s = rem / 64, lane = rem % 64;
        const int m = lane & 15, quad = lane >> 4;
        const int hh = tile * 16 + m;
        f16x8 a;
        #pragma unroll
        for (int j = 0; j < 8; ++j)
            a[j] = (f16)(hh < 50 ? wl1[hh * 320 + s * 32 + quad * 8 + j] : 0.f);
        wl1pk[e] = a;
    }
}

__global__ __launch_bounds__(THREADS, 4)   // 4 waves/EU -> 128 regs/lane cap
void lenet_one(const float* __restrict__ x,
               const unsigned char* __restrict__ ws, const float* __restrict__ b1,
               const float* __restrict__ b2,
               const float* __restrict__ bl1,
               const float* __restrict__ wl2, const float* __restrict__ bl2,
               float* __restrict__ out, int batch)
{
    __shared__ __align__(16) unsigned char p1c[SMEM_BYTES];
    f16*   p2h = (f16*)p1c;             // [img][k 320 pad 328], aliases p1c
    float* h1  = (float*)(p1c + 2624);  // [img][50 pad 52],     aliases p1c

    const uint*  w1pk  = (const uint*)ws;
    const f16x8* w2af  = (const f16x8*)(ws + 1024);
    const f16x8* wl1pk = (const f16x8*)(ws + 17408);

    const int tid = threadIdx.x;
    const int lane = tid & 63;
    const int wv_ = tid >> 6;                 // wave id 0..1
    const int cM = lane & 31, hK = lane >> 5; // conv2 MFMA: row m=cM, K-half hK
    const int img = tid & 3;
    const int imgg = min(blockIdx.x * IPB + img, batch - 1);

    // ---------- conv1 (1->10ch) packed f16 + bias + relu + pool ---------------
    // Row-streamed 2-row pipeline, ALL 10 channels in one pass. Peak live
    // ~52 regs (accT[10]+accB[10]+pa[5]+pb[5]+row temps+addr): fits the 128
    // cap with 2x headroom -> no spills. Each w1pk scalar read feeds both
    // accT (pool row top) and accB (bottom). Accumulation order = R0 conv1.
    {
        const int grp = tid >> 2;                 // 0..31 position groups
        const float* xim = x + (size_t)imgg * 784;
        for (int pq = grp; pq < 144; pq += 32) {  // 4-5 iterations
            const int py = pq / 12, px = pq % 12;
            const float* xb = xim + (2 * py) * 28 + 2 * px;
            f16x2 accT[10], accB[10];
            #pragma unroll
            for (int c = 0; c < 10; ++c) {
                accT[c] = {(f16)0.f, (f16)0.f};
                accB[c] = {(f16)0.f, (f16)0.f};
            }
            f16x2 pa[5], pb[5];
            loadrow(xb, pa);
            #pragma unroll
            for (int wr = 0; wr < 5; ++wr) {
                loadrow(xb + (wr + 1) * 28, pb);
                #pragma unroll
                for (int c = 0; c < 10; ++c) {
                    #pragma unroll
                    for (int kx = 0; kx < 5; ++kx) {
                        const f16x2 wv = __builtin_bit_cast(
                            f16x2, w1pk[c * 25 + wr * 5 + kx]);
                        accT[c] += pa[kx] * wv;      // v_pk_fma_f16
                        accB[c] += pb[kx] * wv;
                    }
                }
                #pragma unroll
                for (int k = 0; k < 5; ++k) pa[k] = pb[k];
            }
            f16 ch[10];
            #pragma unroll
            for (int c = 0; c < 10; ++c) {
                const float q0 = fmaxf((float)accT[c][0], (float)accB[c][0]);
                const float q1 = fmaxf((float)accT[c][1], (float)accB[c][1]);
                ch[c] = (f16)fmaxf(fmaxf(q0, q1) + b1[c], 0.f);
            }
            f16x8 v0, v1;
            #pragma unroll
            for (int j = 0; j < 8; ++j) v0[j] = ch[j];
            v1[0] = ch[8]; v1[1] = ch[9];
            #pragma unroll
            for (int j = 2; j < 8; ++j) v1[j] = (f16)0.f;   // K-pad zeros
            unsigned char* dst = p1c + img * P1_IMG + py * P1_ROW + px * 32;
            *(f16x8*)(dst)      = v0;
            *(f16x8*)(dst + 16) = v1;
        }
    }
    __syncthreads();

    // ---------- conv2 via mfma_f32_32x32x16_f16, 4 tiles/wave ----------------
    // 8 output tiles (4 img x 2 halves), t = wv_*4 + q. One f32x16 acc live
    // at a time (16 AGPR); pool+bias+relu packs to f16x2 immediately so the
    // next tile reuses the AGPRs. pk[4][8] = 16 VGPRs held across barrier.
    {
        const int cy = cM >> 3, cx = cM & 7;
        const int afoff = (cM < 20 ? cM : 19) * 2 + hK;
        f16x2 pk[4][8];                     // pooled+bias+relu, packed f16
        #pragma unroll
        for (int q = 0; q < 4; ++q) {
            const int t = wv_ * 4 + q;
            const int im = t >> 1, h2 = t & 1;
            const int bb = im * P1_IMG + (4 * h2 + cy) * P1_ROW + cx * 32
                         + hK * 16;
            f32x16 acc;
            #pragma unroll
            for (int r = 0; r < 16; ++r) acc[r] = 0.f;
            #pragma unroll 1
            for (int ky = 0; ky < 5; ++ky) {
                #pragma unroll
                for (int kx = 0; kx < 5; ++kx) {
                    const f16x8 a = w2af[(ky * 5 + kx) * 40 + afoff];
                    const f16x8 b =
                        *(const f16x8*)(p1c + bb + ky * P1_ROW + kx * 32);
                    acc = __builtin_amdgcn_mfma_f32_32x32x16_f16(a, b, acc,
                                                                 0, 0, 0);
                }
            }
            #pragma unroll
            for (int r = 0; r < 16; ++r) {
                const int m = (r & 3) + 8 * (r >> 2) + 4 * hK;
                float v = acc[r];
                v = dppmax<0xB1>(v);    // xor1: quad_perm(1,0,3,2)
                v = dppmax<0x128>(v);   // xor8: row_ror:8
                const float bv = b2[min(m, 19)];
                pk[q][r >> 1][r & 1] = (f16)fmaxf(v + bv, 0.f);
            }
        }
        // all waves done READING p1c before writes (p2h aliases p1c)
        __syncthreads();
        #pragma unroll
        for (int q = 0; q < 4; ++q) {
            const int t = wv_ * 4 + q;
            const int im = t >> 1, h2 = t & 1;
            #pragma unroll
            for (int r = 0; r < 16; ++r) {
                const int m = (r & 3) + 8 * (r >> 2) + 4 * hK;
                if (m < 20 && (lane & 9) == 0) {
                    const int py = 2 * h2 + (cM >> 4), px = cx >> 1;
                    p2h[im * 328 + m * 16 + py * 4 + px] = pk[q][r >> 1][r & 1];
                }
            }
        }
    }
    __syncthreads();

    // ---------- fc1 via mfma_f32_16x16x32_f16: M=h tiles, N=img, K=320 --------
    // 4 M-tiles of 16 rows over 2 waves: wave w does tiles {2w, 2w+1}.
    {
        const int n = lane & 15, quad = lane >> 4;
        #pragma unroll
        for (int tt = 0; tt < 2; ++tt) {
            const int tile = wv_ * 2 + tt;
            f32x4 facc = {0.f, 0.f, 0.f, 0.f};
            #pragma unroll 1
            for (int s = 0; s < 10; ++s) {
                const f16x8 a = wl1pk[(tile * 10 + s) * 64 + lane]; // b128
                f16x8 b = {};
                if (n < IPB)
                    b = *(const f16x8*)(p2h + n * 328 + s * 32 + quad * 8);
                facc = __builtin_amdgcn_mfma_f32_16x16x32_f16(a, b, facc,
                                                              0, 0, 0);
            }
            if (n < IPB) {
                #pragma unroll
                for (int r = 0; r < 4; ++r) {
                    const int h = tile * 16 + quad * 4 + r;
                    if (h < 50)
                        h1[n * 52 + h] = fmaxf(facc[r] + bl1[h], 0.f);
                }
            }
        }
    }
    __syncthreads();

    // ---------- fc2: 50->10 ---------------------------------------------------
    if (tid < IPB * 10) {
        const int im = tid / 10, o = tid % 10;
        const int imgo = min(blockIdx.x * IPB + im, batch - 1);
        float a = bl2[o];
        #pragma unroll
        for (int h = 0; h < 50; ++h)
            a += h1[im * 52 + h] * wl2[o * 50 + h];
        out[(size_t)imgo * 10 + o] = a;          // coalesced
    }
}

extern "C" void kernel_launch(void* const* d_in, const int* in_sizes, int n_in,
                              void* d_out, int out_size, void* d_ws, size_t ws_size,
                              hipStream_t stream) {
    const float* x   = (const float*)d_in[0];
    const float* w1  = (const float*)d_in[1];
    const float* b1  = (const float*)d_in[2];
    const float* w2  = (const float*)d_in[3];
    const float* b2  = (const float*)d_in[4];
    const float* wl1 = (const float*)d_in[5];
    const float* bl1 = (const float*)d_in[6];
    const float* wl2 = (const float*)d_in[7];
    const float* bl2 = (const float*)d_in[8];
    float* out = (float*)d_out;
    unsigned char* ws = (unsigned char*)d_ws;   // 58 KB of packed weights

    const int batch = in_sizes[0] / 784;  // 8192
    pack_weights<<<64, 256, 0, stream>>>(w1, w2, wl1, ws);
    const int grid = (batch + IPB - 1) / IPB;
    lenet_one<<<grid, THREADS, 0, stream>>>(x, ws, b1, b2, bl1, wl2, bl2,
                                            out, batch);
}

// Round 8
// 124.382 us; speedup vs baseline: 1.3977x; 1.3977x over previous
//
#include <hip/hip_runtime.h>

#define THREADS 256
#define IPB 4   // images per block; grid = 8192/4 = 2048 = 256 CU x 8 (one round)

typedef _Float16 f16;
typedef _Float16 f16x2 __attribute__((ext_vector_type(2)));
typedef _Float16 f16x4 __attribute__((ext_vector_type(4)));
typedef _Float16 f16x8 __attribute__((ext_vector_type(8)));
typedef float f32x2 __attribute__((ext_vector_type(2)));
typedef float f32x4 __attribute__((ext_vector_type(4)));
typedef float f32x16 __attribute__((ext_vector_type(16)));
typedef unsigned int uint;

__device__ __forceinline__ f16x2 pkrtz(float a, float b) {
    return __builtin_bit_cast(f16x2, __builtin_amdgcn_cvt_pkrtz(a, b));
}
template<int CTRL>
__device__ __forceinline__ float dppmax(float v) {   // fmax with DPP-shuffled lane
    const int i = __builtin_bit_cast(int, v);
    const int s = __builtin_amdgcn_update_dpp(i, i, CTRL, 0xF, 0xF, true);
    return fmaxf(v, __builtin_bit_cast(float, s));
}
// read 8 consecutive f16 window cols from the shifted-pairs image: pairs[c] =
// (xh[c], xh[c+1]) so cols ox..ox+7 = pairs{ox,ox+2,ox+4,ox+6}; every read is
// 4B-aligned for ANY ox (this is the whole point of the pairs layout).
__device__ __forceinline__ f16x8 ldpairs(const unsigned char* a) {
    const uint* p = (const uint*)a;
    uint4 u;
    u.x = p[0]; u.y = p[2]; u.z = p[4]; u.w = p[6];
    return __builtin_bit_cast(f16x8, u);
}

// p1 (pooled conv1 out): [img][iy 12][ix 12][ic 12] f16. ic 10,11 are junk
// slots (conv2 weights for ic>=10 are zero, so values only need to be finite).
#define P1C 24
#define P1R 288
#define P1I 3456   // 4 imgs = 13824 B
// pairs region: [imL 2][row 28][pair 28] f16x2 (112 B/row, 3136 B/img),
// staged twice (2 images per conv1 sub-phase). Tail [20096,20224) zeroed:
// padded-window reads overrun up to ~40 B past the last row; they multiply
// zero weights but must be FINITE (NaN*0 = NaN in MFMA).
#define XH  13824
#define XH_IMG 3136
#define SMEM_BYTES 20224   // 8 blocks/CU: 161792 <= 163840

// d_ws layout (offsets unchanged from prior rounds; [0,1024) now unused):
//   [1024)   w2af   1000 x f16x8  (conv2 A-frags [s][oc*2+hK])
//   [17408)  wl1pk  2560 x f16x8  (fc1 A-frags [tile][s][lane])
__global__ void pack_weights(const float* __restrict__ w1,
                             const float* __restrict__ w2,
                             const float* __restrict__ wl1,
                             unsigned char* __restrict__ ws) {
    f16x8* w2af = (f16x8*)(ws + 1024);
    f16x8* wl1pk = (f16x8*)(ws + 17408);
    const int gid = blockIdx.x * blockDim.x + threadIdx.x;
    const int gsz = gridDim.x * blockDim.x;
    for (int e = gid; e < 1000; e += gsz) {          // conv2 A-frags
        const int s = e / 40, r = e - s * 40;
        const int oc = r >> 1, h = r & 1;
        f16x8 a;
        #pragma unroll
        for (int j = 0; j < 8; ++j) {
            const int ic = h * 8 + j;
            a[j] = (f16)(ic < 10 ? w2[(oc * 10 + ic) * 25 + s] : 0.f);
        }
        w2af[e] = a;
    }
    for (int e = gid; e < 2560; e += gsz) {          // fc1 A-frags
        const int tile = e / 640, rem = e % 640;
        const int s = rem / 64, lane = rem % 64;
        const int m = lane & 15, quad = lane >> 4;
        const int hh = tile * 16 + m;
        f16x8 a;
        #pragma unroll
        for (int j = 0; j < 8; ++j)
            a[j] = (f16)(hh < 50 ? wl1[hh * 320 + s * 32 + quad * 8 + j] : 0.f);
        wl1pk[e] = a;
    }
}

__global__ __launch_bounds__(THREADS, 8)
void lenet_one(const float* __restrict__ x,
               const unsigned char* __restrict__ ws,
               const float* __restrict__ w1, const float* __restrict__ b1,
               const float* __restrict__ b2,
               const float* __restrict__ bl1,
               const float* __restrict__ wl2, const float* __restrict__ bl2,
               float* __restrict__ out, int batch)
{
    __shared__ __align__(16) unsigned char smem[SMEM_BYTES];
    f16*   p2h = (f16*)smem;             // [img][k 320 pad 328], aliases p1
    float* h1  = (float*)(smem + 2624);  // [img][50 pad 52],     aliases p1

    const f16x8* w2af  = (const f16x8*)(ws + 1024);
    const f16x8* wl1pk = (const f16x8*)(ws + 17408);

    const int tid = threadIdx.x;
    const int lane = tid & 63;
    const int wv_ = tid >> 6;                 // wave id 0..3
    const int n15 = lane & 15;                // A-frag oc / B-frag position
    const int q4  = lane >> 4;                // quad
    const int cM = lane & 31, hK = lane >> 5; // conv2 MFMA roles

    // ---------- conv1 A-fragments, built once from global (registers) --------
    // K layout chunk1: k = wrow*8 + wcol (wrow 0..3, wcol 5..7 zero).
    // chunk2: k<8 -> wrow4; slot (q=1,j=0) carries the BIAS (B supplies 1.0):
    // bias folds into the matmul for free; max(a+b,c+b)=max(a,c)+b exactly.
    f16x8 A1 = {}, A2 = {};
    if (n15 < 10) {
        #pragma unroll
        for (int j = 0; j < 5; ++j) A1[j] = (f16)w1[n15 * 25 + q4 * 5 + j];
        if (q4 == 0) {
            #pragma unroll
            for (int j = 0; j < 5; ++j) A2[j] = (f16)w1[n15 * 25 + 20 + j];
        }
        if (q4 == 1) A2[0] = (f16)b1[n15];
    }

    // ---------- conv1 via MFMA, two sub-phases of 2 images each --------------
    #pragma unroll 1
    for (int sub = 0; sub < 2; ++sub) {
        // stage x as shifted f16 pairs (coalesced f32x2 loads, ds_write_b64)
        if (tid < 112) {
            const int imL = tid / 56, rr = (tid % 56) >> 1, half = tid & 1;
            const int ig = min(blockIdx.x * IPB + sub * 2 + imL, batch - 1);
            const float* xp = x + (size_t)ig * 784 + rr * 28 + half * 14;
            float v[15];
            #pragma unroll
            for (int t = 0; t < 7; ++t) {
                const f32x2 a = *(const f32x2*)(xp + 2 * t);
                v[2 * t] = a[0]; v[2 * t + 1] = a[1];
            }
            v[14] = half ? 0.f : xp[14];
            uint* pw = (uint*)(smem + XH + imL * XH_IMG + rr * 112) + half * 14;
            #pragma unroll
            for (int t = 0; t < 7; ++t) {
                uint2 w;
                w.x = __builtin_bit_cast(uint, pkrtz(v[2 * t], v[2 * t + 1]));
                w.y = __builtin_bit_cast(uint, pkrtz(v[2 * t + 1], v[2 * t + 2]));
                *(uint2*)(pw + 2 * t) = w;
            }
        } else if (tid >= 224) {   // finite zero tail for padded-window reads
            *(uint*)(smem + XH + 2 * XH_IMG + (tid - 224) * 4) = 0;
        }
        __syncthreads();

        // 48 pool-groups (2 img x 12 pool-rows x 2 ox-groups) over 4 waves
        #pragma unroll 1
        for (int i = 0; i < 12; ++i) {
            const int g = wv_ * 12 + i;
            const int imL = g / 24, rem = g % 24, u = rem >> 1, oxg = rem & 1;
            const int ox = oxg * 16 + n15;
            const unsigned char* pb = smem + XH + imL * XH_IMG + ox * 4;
            const int oy0 = 2 * u;
            const f16x8 B1a = ldpairs(pb + (oy0 + q4) * 112);
            const f16x8 B1b = ldpairs(pb + (oy0 + 1 + q4) * 112);
            f16x8 B2a = {}, B2b = {};
            if (q4 == 0) {
                B2a = ldpairs(pb + (oy0 + 4) * 112);
                B2b = ldpairs(pb + (oy0 + 5) * 112);
            } else if (q4 == 1) {
                B2a[0] = (f16)1.f; B2b[0] = (f16)1.f;   // bias lane
            }
            f32x4 aa = {0.f, 0.f, 0.f, 0.f}, ab = {0.f, 0.f, 0.f, 0.f};
            aa = __builtin_amdgcn_mfma_f32_16x16x32_f16(A1, B1a, aa, 0, 0, 0);
            ab = __builtin_amdgcn_mfma_f32_16x16x32_f16(A1, B1b, ab, 0, 0, 0);
            aa = __builtin_amdgcn_mfma_f32_16x16x32_f16(A2, B2a, aa, 0, 0, 0);
            ab = __builtin_amdgcn_mfma_f32_16x16x32_f16(A2, B2b, ab, 0, 0, 0);
            // pool (rows in-register, cols via DPP xor1) + relu
            float vr[4];
            #pragma unroll
            for (int r = 0; r < 4; ++r) {
                float v = fmaxf(aa[r], ab[r]);
                v = dppmax<0xB1>(v);               // lane n <-> n^1
                vr[r] = fmaxf(v, 0.f);
            }
            if (!(lane & 1) && q4 < 3 && (oxg == 0 || n15 < 8)) {
                const int im = sub * 2 + imL, px = oxg * 8 + (n15 >> 1);
                f16x2 o0, o1;
                o0[0] = (f16)vr[0]; o0[1] = (f16)vr[1];
                o1[0] = (f16)vr[2]; o1[1] = (f16)vr[3];
                uint2 w;
                w.x = __builtin_bit_cast(uint, o0);
                w.y = __builtin_bit_cast(uint, o1);
                *(uint2*)(smem + im * P1I + u * P1R + px * P1C + q4 * 8) = w;
            }
        }
        __syncthreads();
    }

    // ---------- conv2 via mfma_f32_32x32x16_f16 (2 tiles/wave, R2 form) ------
    {
        const int cy = cM >> 3, cx = cM & 7;
        const int afoff = (cM < 20 ? cM : 19) * 2 + hK;
        int bb[2];
        #pragma unroll
        for (int q = 0; q < 2; ++q) {
            const int t = wv_ * 2 + q, im = t >> 1, h2 = t & 1;
            bb[q] = im * P1I + (4 * h2 + cy) * P1R + cx * P1C + hK * 16;
        }
        f32x16 acc[2];
        #pragma unroll
        for (int q = 0; q < 2; ++q)
            #pragma unroll
            for (int r = 0; r < 16; ++r) acc[q][r] = 0.f;
        #pragma unroll 1
        for (int ky = 0; ky < 5; ++ky) {
            #pragma unroll
            for (int kx = 0; kx < 5; ++kx) {
                const f16x8 a = w2af[(ky * 5 + kx) * 40 + afoff];
                #pragma unroll
                for (int q = 0; q < 2; ++q) {
                    const unsigned char* ad = smem + bb[q] + ky * P1R + kx * P1C;
                    const f16x4 lo = *(const f16x4*)(ad);
                    const f16x4 hi = *(const f16x4*)(ad + 8);  // ic12..15: junk x 0-weights
                    f16x8 b;
                    #pragma unroll
                    for (int j = 0; j < 4; ++j) { b[j] = lo[j]; b[4 + j] = hi[j]; }
                    acc[q] = __builtin_amdgcn_mfma_f32_32x32x16_f16(a, b, acc[q],
                                                                    0, 0, 0);
                }
            }
        }
        // all waves done READING p1 before epilogue overwrites it (p2h alias)
        __syncthreads();
        #pragma unroll
        for (int q = 0; q < 2; ++q) {
            const int t = wv_ * 2 + q, im = t >> 1, h2 = t & 1;
            #pragma unroll
            for (int r = 0; r < 16; ++r) {
                const int m = (r & 3) + 8 * (r >> 2) + 4 * hK;
                float v = acc[q][r];
                v = dppmax<0xB1>(v);    // xor1: quad_perm(1,0,3,2)
                v = dppmax<0x128>(v);   // xor8: row_ror:8
                if (m < 20 && (lane & 9) == 0) {
                    const int py = 2 * h2 + (cM >> 4), px = cx >> 1;
                    p2h[im * 328 + m * 16 + py * 4 + px] =
                        (f16)fmaxf(v + b2[m], 0.f);
                }
            }
        }
    }
    __syncthreads();

    // ---------- fc1 via mfma_f32_16x16x32_f16: M=h tile/wave, N=img, K=320 ----
    {
        f32x4 facc = {0.f, 0.f, 0.f, 0.f};
        #pragma unroll 1
        for (int s = 0; s < 10; ++s) {
            const f16x8 a = wl1pk[(wv_ * 10 + s) * 64 + lane];  // coalesced b128
            f16x8 b = {};
            if (n15 < IPB)
                b = *(const f16x8*)(p2h + n15 * 328 + s * 32 + q4 * 8);
            facc = __builtin_amdgcn_mfma_f32_16x16x32_f16(a, b, facc, 0, 0, 0);
        }
        if (n15 < IPB) {
            #pragma unroll
            for (int r = 0; r < 4; ++r) {
                const int h = wv_ * 16 + q4 * 4 + r;
                if (h < 50)
                    h1[n15 * 52 + h] = fmaxf(facc[r] + bl1[h], 0.f);
            }
        }
    }
    __syncthreads();

    // ---------- fc2: 50->10 ---------------------------------------------------
    if (tid < IPB * 10) {
        const int im = tid / 10, o = tid % 10;
        const int imgo = min(blockIdx.x * IPB + im, batch - 1);
        float a = bl2[o];
        #pragma unroll
        for (int h = 0; h < 50; ++h)
            a += h1[im * 52 + h] * wl2[o * 50 + h];
        out[(size_t)imgo * 10 + o] = a;          // coalesced
    }
}

extern "C" void kernel_launch(void* const* d_in, const int* in_sizes, int n_in,
                              void* d_out, int out_size, void* d_ws, size_t ws_size,
                              hipStream_t stream) {
    const float* x   = (const float*)d_in[0];
    const float* w1  = (const float*)d_in[1];
    const float* b1  = (const float*)d_in[2];
    const float* w2  = (const float*)d_in[3];
    const float* b2  = (const float*)d_in[4];
    const float* wl1 = (const float*)d_in[5];
    const float* bl1 = (const float*)d_in[6];
    const float* wl2 = (const float*)d_in[7];
    const float* bl2 = (const float*)d_in[8];
    float* out = (float*)d_out;
    unsigned char* ws = (unsigned char*)d_ws;

    const int batch = in_sizes[0] / 784;  // 8192
    pack_weights<<<64, 256, 0, stream>>>(w1, w2, wl1, ws);
    const int grid = (batch + IPB - 1) / IPB;
    lenet_one<<<grid, THREADS, 0, stream>>>(x, ws, w1, b1, b2, bl1, wl2, bl2,
                                            out, batch);
}

// Round 9
// 119.561 us; speedup vs baseline: 1.4540x; 1.0403x over previous
//
#include <hip/hip_runtime.h>

#define THREADS 256
#define IPB 4   // images per block; grid = 8192/4 = 2048 = 256 CU x 8 (one round)

typedef _Float16 f16;
typedef _Float16 f16x2 __attribute__((ext_vector_type(2)));
typedef _Float16 f16x4 __attribute__((ext_vector_type(4)));
typedef _Float16 f16x8 __attribute__((ext_vector_type(8)));
typedef float f32x2 __attribute__((ext_vector_type(2)));
typedef float f32x4 __attribute__((ext_vector_type(4)));
typedef float f32x16 __attribute__((ext_vector_type(16)));
typedef unsigned int uint;

__device__ __forceinline__ f16x2 pkrtz(float a, float b) {
    return __builtin_bit_cast(f16x2, __builtin_amdgcn_cvt_pkrtz(a, b));
}
template<int CTRL>
__device__ __forceinline__ float dppmax(float v) {   // fmax with DPP-shuffled lane
    const int i = __builtin_bit_cast(int, v);
    const int s = __builtin_amdgcn_update_dpp(i, i, CTRL, 0xF, 0xF, true);
    return fmaxf(v, __builtin_bit_cast(float, s));
}
// read 8 consecutive f16 window cols from the shifted-pairs image: pairs[c] =
// (xh[c], xh[c+1]) so cols ox..ox+7 = pairs{ox,ox+2,ox+4,ox+6}; every read is
// 4B-aligned for ANY ox.
__device__ __forceinline__ f16x8 ldpairs(const unsigned char* a) {
    const uint* p = (const uint*)a;
    uint4 u;
    u.x = p[0]; u.y = p[2]; u.z = p[4]; u.w = p[6];
    return __builtin_bit_cast(f16x8, u);
}

// p1 (pooled conv1 out): [img][iy 12][ix 12][ic 12] f16. ic 10,11 are exact
// zeros (conv1 rows 10-15 have zero weights+bias); conv2 ic>=10 weights are 0.
#define P1C 24
#define P1R 288
#define P1I 3456   // 4 imgs = 13824 B
// pairs region (ROW-INTERLEAVED, R9): [row 28][imL 2][pair 28] f16x2.
// Row stride 224 B = 56 dwords === 24 mod 32 banks -> quad offsets {0,24,16,8}:
// every ldpairs is exactly 2 lanes/bank = conflict-FREE (R8's 112B stride gave
// 4-way pileups on banks 0-3). Same 6272 B total. Tail [20096,20224) zeroed:
// padded-window reads overrun past the last row; they multiply zero weights
// but must be FINITE (NaN*0 = NaN in MFMA).
#define XH  13824
#define SMEM_BYTES 20224   // 8 blocks/CU: 161792 <= 163840

// d_ws layout ([0,1024) unused):
//   [1024)   w2af   1000 x f16x8  (conv2 A-frags [s][oc*2+hK])
//   [17408)  wl1pk  2560 x f16x8  (fc1 A-frags [tile][s][lane])
__global__ void pack_weights(const float* __restrict__ w1,
                             const float* __restrict__ w2,
                             const float* __restrict__ wl1,
                             unsigned char* __restrict__ ws) {
    f16x8* w2af = (f16x8*)(ws + 1024);
    f16x8* wl1pk = (f16x8*)(ws + 17408);
    const int gid = blockIdx.x * blockDim.x + threadIdx.x;
    const int gsz = gridDim.x * blockDim.x;
    for (int e = gid; e < 1000; e += gsz) {          // conv2 A-frags
        const int s = e / 40, r = e - s * 40;
        const int oc = r >> 1, h = r & 1;
        f16x8 a;
        #pragma unroll
        for (int j = 0; j < 8; ++j) {
            const int ic = h * 8 + j;
            a[j] = (f16)(ic < 10 ? w2[(oc * 10 + ic) * 25 + s] : 0.f);
        }
        w2af[e] = a;
    }
    for (int e = gid; e < 2560; e += gsz) {          // fc1 A-frags
        const int tile = e / 640, rem = e % 640;
        const int s = rem / 64, lane = rem % 64;
        const int m = lane & 15, quad = lane >> 4;
        const int hh = tile * 16 + m;
        f16x8 a;
        #pragma unroll
        for (int j = 0; j < 8; ++j)
            a[j] = (f16)(hh < 50 ? wl1[hh * 320 + s * 32 + quad * 8 + j] : 0.f);
        wl1pk[e] = a;
    }
}

__global__ __launch_bounds__(THREADS, 8)
void lenet_one(const float* __restrict__ x,
               const unsigned char* __restrict__ ws,
               const float* __restrict__ w1, const float* __restrict__ b1,
               const float* __restrict__ b2,
               const float* __restrict__ bl1,
               const float* __restrict__ wl2, const float* __restrict__ bl2,
               float* __restrict__ out, int batch)
{
    __shared__ __align__(16) unsigned char smem[SMEM_BYTES];
    f16*   p2h = (f16*)smem;             // [img][k 320 pad 328], aliases p1
    float* h1  = (float*)(smem + 2624);  // [img][50 pad 52],     aliases p1

    const f16x8* w2af  = (const f16x8*)(ws + 1024);
    const f16x8* wl1pk = (const f16x8*)(ws + 17408);

    const int tid = threadIdx.x;
    const int lane = tid & 63;
    const int wv_ = tid >> 6;                 // wave id 0..3
    const int n15 = lane & 15;                // A-frag oc / B-frag position
    const int q4  = lane >> 4;                // quad
    const int cM = lane & 31, hK = lane >> 5; // conv2 MFMA roles

    // ---------- conv1 A-fragments, built once from global (registers) --------
    // chunk1: k = wrow*8 + wcol (wrow 0..3, wcol 5..7 zero).
    // chunk2: k<8 -> wrow4; slot (q=1,j=0) carries the BIAS (B supplies 1.0):
    // max(a+b,c+b)=max(a,c)+b exactly, so bias folds before pooling.
    f16x8 A1 = {}, A2 = {};
    if (n15 < 10) {
        #pragma unroll
        for (int j = 0; j < 5; ++j) A1[j] = (f16)w1[n15 * 25 + q4 * 5 + j];
        if (q4 == 0) {
            #pragma unroll
            for (int j = 0; j < 5; ++j) A2[j] = (f16)w1[n15 * 25 + 20 + j];
        }
        if (q4 == 1) A2[0] = (f16)b1[n15];
    }

    // ---------- conv1 via MFMA, two sub-phases of 2 images each --------------
    #pragma unroll 1
    for (int sub = 0; sub < 2; ++sub) {
        // stage x as shifted f16 pairs, row-interleaved across the 2 images.
        // tid -> (rr=tid>>2, imL=(tid>>1)&1, half=tid&1): dword offset = 14*tid
        // -> 16 distinct banks per 16 lanes, 2-way max on writes (free).
        if (tid < 112) {
            const int rr = tid >> 2, imL = (tid >> 1) & 1, half = tid & 1;
            const int ig = min(blockIdx.x * IPB + sub * 2 + imL, batch - 1);
            const float* xp = x + (size_t)ig * 784 + rr * 28 + half * 14;
            float v[15];
            #pragma unroll
            for (int t = 0; t < 7; ++t) {
                const f32x2 a = *(const f32x2*)(xp + 2 * t);
                v[2 * t] = a[0]; v[2 * t + 1] = a[1];
            }
            v[14] = half ? 0.f : xp[14];
            uint* pw = (uint*)(smem + XH + rr * 224 + imL * 112) + half * 14;
            #pragma unroll
            for (int t = 0; t < 7; ++t) {
                uint2 w;
                w.x = __builtin_bit_cast(uint, pkrtz(v[2 * t], v[2 * t + 1]));
                w.y = __builtin_bit_cast(uint, pkrtz(v[2 * t + 1], v[2 * t + 2]));
                *(uint2*)(pw + 2 * t) = w;
            }
        } else if (tid >= 224) {   // finite zero tail for padded-window reads
            *(uint*)(smem + XH + 28 * 224 + (tid - 224) * 4) = 0;
        }
        __syncthreads();

        // pool loop: wave = (imL = wv>>1, oxg = wv&1); u = 11..0 fully
        // unrolled -> every LDS address is base + compile-time immediate.
        // B2 rows (2u+4, 2u+5) = quad0's B1 rows of iteration u+2 -> 2-deep
        // named-register history (u=11,10 read direct). Non-quad0 lanes get
        // junk-but-finite values that multiply A2's zero weights.
        {
            const int imL = wv_ >> 1, oxg = wv_ & 1;
            const int ox = oxg * 16 + n15;
            const int im = sub * 2 + imL;
            const unsigned char* pb = smem + XH + imL * 112 + ox * 4
                                    + q4 * 224;           // + row offset base
            unsigned char* wbase = smem + im * P1I;
            f16x8 hA0 = {}, hB0 = {}, hA1 = {}, hB1 = {};
            #pragma unroll
            for (int uu = 0; uu < 12; ++uu) {
                const int u = 11 - uu;
                const f16x8 B1a = ldpairs(pb + (2 * u) * 224);
                const f16x8 B1b = ldpairs(pb + (2 * u + 1) * 224);
                f16x8 B2a, B2b;
                if (u >= 10) {   // compile-time branch
                    B2a = ldpairs(pb - q4 * 224 + (2 * u + 4) * 224);
                    B2b = ldpairs(pb - q4 * 224 + (2 * u + 5) * 224);
                } else {
                    B2a = (u & 1) ? hA1 : hA0;
                    B2b = (u & 1) ? hB1 : hB0;
                }
                if (u & 1) { hA1 = B1a; hB1 = B1b; }
                else       { hA0 = B1a; hB0 = B1b; }
                if (q4 == 1) { B2a[0] = (f16)1.f; B2b[0] = (f16)1.f; } // bias
                f32x4 aa = {0.f, 0.f, 0.f, 0.f}, ab = {0.f, 0.f, 0.f, 0.f};
                aa = __builtin_amdgcn_mfma_f32_16x16x32_f16(A1, B1a, aa, 0, 0, 0);
                ab = __builtin_amdgcn_mfma_f32_16x16x32_f16(A1, B1b, ab, 0, 0, 0);
                aa = __builtin_amdgcn_mfma_f32_16x16x32_f16(A2, B2a, aa, 0, 0, 0);
                ab = __builtin_amdgcn_mfma_f32_16x16x32_f16(A2, B2b, ab, 0, 0, 0);
                // pool (rows in-register, cols via DPP xor1) + relu
                float vr[4];
                #pragma unroll
                for (int r = 0; r < 4; ++r) {
                    float v = fmaxf(aa[r], ab[r]);
                    v = dppmax<0xB1>(v);               // lane n <-> n^1
                    vr[r] = fmaxf(v, 0.f);
                }
                if (!(lane & 1) && q4 < 3 && (oxg == 0 || n15 < 8)) {
                    const int px = oxg * 8 + (n15 >> 1);
                    f16x2 o0, o1;
                    o0[0] = (f16)vr[0]; o0[1] = (f16)vr[1];
                    o1[0] = (f16)vr[2]; o1[1] = (f16)vr[3];
                    uint2 w;
                    w.x = __builtin_bit_cast(uint, o0);
                    w.y = __builtin_bit_cast(uint, o1);
                    *(uint2*)(wbase + u * P1R + px * P1C + q4 * 8) = w;
                }
            }
        }
        __syncthreads();
    }

    // ---------- conv2 via mfma_f32_32x32x16_f16 (2 tiles/wave, R8 form) ------
    {
        const int cy = cM >> 3, cx = cM & 7;
        const int afoff = (cM < 20 ? cM : 19) * 2 + hK;
        int bb[2];
        #pragma unroll
        for (int q = 0; q < 2; ++q) {
            const int t = wv_ * 2 + q, im = t >> 1, h2 = t & 1;
            bb[q] = im * P1I + (4 * h2 + cy) * P1R + cx * P1C + hK * 16;
        }
        f32x16 acc[2];
        #pragma unroll
        for (int q = 0; q < 2; ++q)
            #pragma unroll
            for (int r = 0; r < 16; ++r) acc[q][r] = 0.f;
        #pragma unroll 1
        for (int ky = 0; ky < 5; ++ky) {
            #pragma unroll
            for (int kx = 0; kx < 5; ++kx) {
                const f16x8 a = w2af[(ky * 5 + kx) * 40 + afoff];
                #pragma unroll
                for (int q = 0; q < 2; ++q) {
                    const unsigned char* ad = smem + bb[q] + ky * P1R + kx * P1C;
                    const f16x4 lo = *(const f16x4*)(ad);
                    const f16x4 hi = *(const f16x4*)(ad + 8); // ic12-15 junk x 0
                    f16x8 b;
                    #pragma unroll
                    for (int j = 0; j < 4; ++j) { b[j] = lo[j]; b[4 + j] = hi[j]; }
                    acc[q] = __builtin_amdgcn_mfma_f32_32x32x16_f16(a, b, acc[q],
                                                                    0, 0, 0);
                }
            }
        }
        // all waves done READING p1 before epilogue overwrites it (p2h alias)
        __syncthreads();
        #pragma unroll
        for (int q = 0; q < 2; ++q) {
            const int t = wv_ * 2 + q, im = t >> 1, h2 = t & 1;
            #pragma unroll
            for (int r = 0; r < 16; ++r) {
                const int m = (r & 3) + 8 * (r >> 2) + 4 * hK;
                float v = acc[q][r];
                v = dppmax<0xB1>(v);    // xor1: quad_perm(1,0,3,2)
                v = dppmax<0x128>(v);   // xor8: row_ror:8
                if (m < 20 && (lane & 9) == 0) {
                    const int py = 2 * h2 + (cM >> 4), px = cx >> 1;
                    p2h[im * 328 + m * 16 + py * 4 + px] =
                        (f16)fmaxf(v + b2[m], 0.f);
                }
            }
        }
    }
    __syncthreads();

    // ---------- fc1 via mfma_f32_16x16x32_f16: M=h tile/wave, N=img, K=320 ----
    {
        f32x4 facc = {0.f, 0.f, 0.f, 0.f};
        #pragma unroll 1
        for (int s = 0; s < 10; ++s) {
            const f16x8 a = wl1pk[(wv_ * 10 + s) * 64 + lane];  // coalesced b128
            f16x8 b = {};
            if (n15 < IPB)
                b = *(const f16x8*)(p2h + n15 * 328 + s * 32 + q4 * 8);
            facc = __builtin_amdgcn_mfma_f32_16x16x32_f16(a, b, facc, 0, 0, 0);
        }
        if (n15 < IPB) {
            #pragma unroll
            for (int r = 0; r < 4; ++r) {
                const int h = wv_ * 16 + q4 * 4 + r;
                if (h < 50)
                    h1[n15 * 52 + h] = fmaxf(facc[r] + bl1[h], 0.f);
            }
        }
    }
    __syncthreads();

    // ---------- fc2: 50->10 ---------------------------------------------------
    if (tid < IPB * 10) {
        const int im = tid / 10, o = tid % 10;
        const int imgo = min(blockIdx.x * IPB + im, batch - 1);
        float a = bl2[o];
        #pragma unroll
        for (int h = 0; h < 50; ++h)
            a += h1[im * 52 + h] * wl2[o * 50 + h];
        out[(size_t)imgo * 10 + o] = a;          // coalesced
    }
}

extern "C" void kernel_launch(void* const* d_in, const int* in_sizes, int n_in,
                              void* d_out, int out_size, void* d_ws, size_t ws_size,
                              hipStream_t stream) {
    const float* x   = (const float*)d_in[0];
    const float* w1  = (const float*)d_in[1];
    const float* b1  = (const float*)d_in[2];
    const float* w2  = (const float*)d_in[3];
    const float* b2  = (const float*)d_in[4];
    const float* wl1 = (const float*)d_in[5];
    const float* bl1 = (const float*)d_in[6];
    const float* wl2 = (const float*)d_in[7];
    const float* bl2 = (const float*)d_in[8];
    float* out = (float*)d_out;
    unsigned char* ws = (unsigned char*)d_ws;

    const int batch = in_sizes[0] / 784;  // 8192
    pack_weights<<<64, 256, 0, stream>>>(w1, w2, wl1, ws);
    const int grid = (batch + IPB - 1) / IPB;
    lenet_one<<<grid, THREADS, 0, stream>>>(x, ws, w1, b1, b2, bl1, wl2, bl2,
                                            out, batch);
}